// Round 2
// baseline (793.831 us; speedup 1.0000x reference)
//
#include <hip/hip_runtime.h>
#include <stdint.h>

// MultiheadCorrelation: T=8192, B=4, D=1024, H=16, hd=64. fp32 I/O.
// Internal compute in bf16 MFMA (2% absmax budget allows it).
// Pipeline: cvt(fp32->bf16 for query/Wqkv/Wout) -> GEMM1(qkv split, bf16 out)
//   -> stats(cov sums, fp32) -> finalize(corr softmax -> corrT bf16)
//   -> attn (v @ corr, MFMA, bf16) -> GEMM2 (out proj, fp32 out).

typedef unsigned short u16;
typedef __attribute__((ext_vector_type(8))) short bf16x8;   // 8 bf16 = 4 VGPRs (MFMA A/B frag)
typedef __attribute__((ext_vector_type(8))) u16  u16x8;
typedef __attribute__((ext_vector_type(4))) float f32x4;    // MFMA C/D frag

#define AS1 __attribute__((address_space(1)))
#define AS3 __attribute__((address_space(3)))

__device__ __forceinline__ float b2f(uint32_t h) {
  union { uint32_t u; float f; } x; x.u = h << 16; return x.f;
}
__device__ __forceinline__ u16 f2b(float f) {
  union { float f; uint32_t u; } x; x.f = f;
  const uint32_t u = x.u;
  return (u16)((u + 0x7FFFu + ((u >> 16) & 1u)) >> 16);  // RNE
}
// async global->LDS, 16B per lane; LDS dest must be uniform base + lane*16
__device__ __forceinline__ void g2l16(const void* g, void* l) {
  __builtin_amdgcn_global_load_lds((const AS1 uint32_t*)g, (AS3 uint32_t*)l, 16, 0, 0);
}

// ---------------------------------------------------------------------------
// fp32 -> bf16 convert, 8 elements/thread, grid-stride.
// ---------------------------------------------------------------------------
__global__ __launch_bounds__(256) void cvt_k(const float* __restrict__ src,
                                             u16* __restrict__ dst, int n8)
{
  for (int i = blockIdx.x * 256 + threadIdx.x; i < n8; i += gridDim.x * 256) {
    const float4 a = *(const float4*)(src + (size_t)i * 8);
    const float4 b = *(const float4*)(src + (size_t)i * 8 + 4);
    u16x8 o;
    o[0] = f2b(a.x); o[1] = f2b(a.y); o[2] = f2b(a.z); o[3] = f2b(a.w);
    o[4] = f2b(b.x); o[5] = f2b(b.y); o[6] = f2b(b.z); o[7] = f2b(b.w);
    *(u16x8*)(dst + (size_t)i * 8) = o;
  }
}

// ---------------------------------------------------------------------------
// GEMM: C[m,n] = sum_k A[m,k]*Bw[n,k] + bias[n]   (A,Bw bf16, K-contig; bias fp32)
// 128x128 tile, BK=32, 4 waves of 64x64, mfma_f32_16x16x32_bf16.
// MODE 0: bf16 [M,N] out. MODE 1: bf16 split into 3 [M,1024] segs by n>>10.
// MODE 2: fp32 [M,N] out.
// ---------------------------------------------------------------------------
template <int MODE>
__global__ __launch_bounds__(256) void gemm_bt(
    const u16* __restrict__ A, const u16* __restrict__ Bw,
    const float* __restrict__ bias, void* __restrict__ OutP,
    int M, int N, int K, int nTilesN)
{
  __shared__ __align__(16) u16 As[128 * 32];
  __shared__ __align__(16) u16 Bs[128 * 32];
  const int tid = threadIdx.x;
  const int bn = blockIdx.x % nTilesN;
  const int bm = blockIdx.x / nTilesN;
  const int m0 = bm * 128, n0 = bn * 128;
  const int lane = tid & 63, wave = tid >> 6;
  const int wm = (wave >> 1) * 64, wn = (wave & 1) * 64;
  const int laneN = lane & 15, laneQ = lane >> 4;

  // staging: each thread issues 2 A + 2 B 16B-wide global_load_lds
  const int rowA = tid >> 2;            // 0..63
  const int kofs = (tid & 3) * 8;       // bf16 elements within BK=32
  const u16* gA0 = A + (size_t)(m0 + rowA) * K + kofs;
  const u16* gA1 = gA0 + (size_t)64 * K;
  const u16* gB0 = Bw + (size_t)(n0 + rowA) * K + kofs;
  const u16* gB1 = gB0 + (size_t)64 * K;
  u16* lA0 = &As[rowA * 32 + kofs];           // byte ofs = tid*16 (wave-uniform + lane*16)
  u16* lA1 = &As[(rowA + 64) * 32 + kofs];
  u16* lB0 = &Bs[rowA * 32 + kofs];
  u16* lB1 = &Bs[(rowA + 64) * 32 + kofs];

  f32x4 acc[4][4] = {};

  for (int kt = 0; kt < K; kt += 32) {
    __syncthreads();                    // protect LDS from prior iter's readers
    g2l16(gA0 + kt, lA0);
    g2l16(gA1 + kt, lA1);
    g2l16(gB0 + kt, lB0);
    g2l16(gB1 + kt, lB1);
    __syncthreads();                    // drains vmcnt before barrier
    bf16x8 af[4], bf[4];
#pragma unroll
    for (int i = 0; i < 4; ++i)
      af[i] = *(const bf16x8*)&As[(wm + i * 16 + laneN) * 32 + laneQ * 8];
#pragma unroll
    for (int j = 0; j < 4; ++j)
      bf[j] = *(const bf16x8*)&Bs[(wn + j * 16 + laneN) * 32 + laneQ * 8];
#pragma unroll
    for (int i = 0; i < 4; ++i)
#pragma unroll
      for (int j = 0; j < 4; ++j)
        acc[i][j] = __builtin_amdgcn_mfma_f32_16x16x32_bf16(af[i], bf[j], acc[i][j], 0, 0, 0);
  }

#pragma unroll
  for (int i = 0; i < 4; ++i) {
#pragma unroll
    for (int j = 0; j < 4; ++j) {
      const int col = n0 + wn + j * 16 + laneN;
      const float bv = bias[col];
#pragma unroll
      for (int r = 0; r < 4; ++r) {
        const int row = m0 + wm + i * 16 + laneQ * 4 + r;  // C/D: col=lane&15, row=quad*4+r
        const float v = acc[i][j][r] + bv;
        if (MODE == 1) {
          const int seg = col >> 10, cc = col & 1023;
          ((u16*)OutP)[(size_t)seg * ((size_t)M * 1024) + (size_t)row * 1024 + cc] = f2b(v);
        } else if (MODE == 0) {
          ((u16*)OutP)[(size_t)row * N + col] = f2b(v);
        } else {
          ((float*)OutP)[(size_t)row * N + col] = v;
        }
      }
    }
  }
}

// ---------------------------------------------------------------------------
// Stats: per (b,h): S_qk[d][e] += q_d(t)*k_e(t); marginals Sq,Sqq,Sk,Skk.
// grid = 64 bh * 16 t-chunks (512 t each), block 256. fp32 accumulate, atomics.
// ---------------------------------------------------------------------------
__global__ __launch_bounds__(256) void stats_k(
    const u16* __restrict__ qb, const u16* __restrict__ kb,
    float* __restrict__ Sqk, float* __restrict__ Smarg)
{
  __shared__ __align__(16) float qs[64][64];
  __shared__ __align__(16) float ks[64][64];
  const int tid = threadIdx.x;
  const int bh = blockIdx.x & 63;
  const int chunk = blockIdx.x >> 6;
  const int b = bh >> 4, h = bh & 15;
  const int t0 = chunk * 512;

  const int ib = tid >> 4, jb = tid & 15;      // 4x4 acc tile: d=ib*4+r, e=jb*4+c
  const int dmarg = tid & 63, quarter = tid >> 6;
  const int lr = tid >> 3, lc = tid & 7;       // staging: 8 threads/row of 64 bf16

  float acc[4][4] = {};
  float sq = 0.f, sqq = 0.f, sk = 0.f, skk = 0.f;

  for (int ts = 0; ts < 512; ts += 64) {
    __syncthreads();
#pragma unroll
    for (int half = 0; half < 2; ++half) {
      const int rr = lr + half * 32;
      const size_t g = (size_t)((t0 + ts + rr) * 4 + b) * 1024 + h * 64 + lc * 8;
      const uint4 rq = *(const uint4*)(qb + g);
      const uint4 rk = *(const uint4*)(kb + g);
      float* dq = &qs[rr][lc * 8];
      float* dk = &ks[rr][lc * 8];
      dq[0] = b2f(rq.x & 0xffffu); dq[1] = b2f(rq.x >> 16);
      dq[2] = b2f(rq.y & 0xffffu); dq[3] = b2f(rq.y >> 16);
      dq[4] = b2f(rq.z & 0xffffu); dq[5] = b2f(rq.z >> 16);
      dq[6] = b2f(rq.w & 0xffffu); dq[7] = b2f(rq.w >> 16);
      dk[0] = b2f(rk.x & 0xffffu); dk[1] = b2f(rk.x >> 16);
      dk[2] = b2f(rk.y & 0xffffu); dk[3] = b2f(rk.y >> 16);
      dk[4] = b2f(rk.z & 0xffffu); dk[5] = b2f(rk.z >> 16);
      dk[6] = b2f(rk.w & 0xffffu); dk[7] = b2f(rk.w >> 16);
    }
    __syncthreads();
    for (int tt = 0; tt < 64; ++tt) {
      const f32x4 qv = *(const f32x4*)&qs[tt][ib * 4];   // broadcast across 16 lanes
      const f32x4 kv = *(const f32x4*)&ks[tt][jb * 4];
#pragma unroll
      for (int r = 0; r < 4; ++r)
#pragma unroll
        for (int c = 0; c < 4; ++c)
          acc[r][c] = fmaf(qv[r], kv[c], acc[r][c]);
    }
#pragma unroll
    for (int q2 = 0; q2 < 16; ++q2) {          // marginals: thread = (d, tt-quarter)
      const int tt = quarter * 16 + q2;
      const float x = qs[tt][dmarg];
      const float y = ks[tt][dmarg];
      sq += x; sqq = fmaf(x, x, sqq);
      sk += y; skk = fmaf(y, y, skk);
    }
  }
  float* S = Sqk + (size_t)bh * 4096;
#pragma unroll
  for (int r = 0; r < 4; ++r)
#pragma unroll
    for (int c = 0; c < 4; ++c)
      atomicAdd(&S[(ib * 4 + r) * 64 + jb * 4 + c], acc[r][c]);
  atomicAdd(&Smarg[0 * 4096 + bh * 64 + dmarg], sq);
  atomicAdd(&Smarg[1 * 4096 + bh * 64 + dmarg], sqq);
  atomicAdd(&Smarg[2 * 4096 + bh * 64 + dmarg], sk);
  atomicAdd(&Smarg[3 * 4096 + bh * 64 + dmarg], skk);
}

// ---------------------------------------------------------------------------
// Finalize: corr[d][e] = softmax_d(clip(cov/sqrt(sx*sy),0,1)); store corrT[e][d] bf16.
// grid 64 (bh), block 64 (thread = e column).
// ---------------------------------------------------------------------------
__global__ __launch_bounds__(64) void finalize_k(
    const float* __restrict__ Sqk, const float* __restrict__ Smarg,
    u16* __restrict__ corrT)
{
  __shared__ float sqs[64], sxs[64];
  __shared__ float rbuf[64 * 64];
  const int bh = blockIdx.x;
  const int e = threadIdx.x;
  const float invT = 1.0f / 8192.0f;
  const float* S = Sqk + (size_t)bh * 4096;
  const float ske  = Smarg[2 * 4096 + bh * 64 + e];
  const float skke = Smarg[3 * 4096 + bh * 64 + e];
  const float sy = skke - ske * ske * invT;
  const float sqe  = Smarg[0 * 4096 + bh * 64 + e];
  const float sqqe = Smarg[1 * 4096 + bh * 64 + e];
  sqs[e] = sqe;
  sxs[e] = sqqe - sqe * sqe * invT;
  __syncthreads();
  float mx = 0.0f;                      // clip lower bound is 0
  for (int d = 0; d < 64; ++d) {
    const float c = S[d * 64 + e] - sqs[d] * ske * invT;
    float r = c / sqrtf(sxs[d] * sy);
    r = fminf(fmaxf(r, 0.0f), 1.0f);
    rbuf[d * 64 + e] = r;
    mx = fmaxf(mx, r);
  }
  float sum = 0.f;
  for (int d = 0; d < 64; ++d) {
    const float ev = expf(rbuf[d * 64 + e] - mx);
    rbuf[d * 64 + e] = ev;
    sum += ev;
  }
  const float inv = 1.0f / sum;
  for (int d = 0; d < 64; ++d)
    corrT[(size_t)bh * 4096 + e * 64 + d] = f2b(rbuf[d * 64 + e] * inv);
}

// ---------------------------------------------------------------------------
// Attn: attn[t,e] = sum_d v[t,d] * corr[d,e] per (b,h). MFMA, A=v (256 t-rows),
// B^T = corrT[e][d]. grid = 64 bh * (T/256). block 256 (4 waves x 64 t-rows).
// ---------------------------------------------------------------------------
__global__ __launch_bounds__(256) void attn_k(
    const u16* __restrict__ vb, const u16* __restrict__ corrT,
    u16* __restrict__ attnb)
{
  __shared__ __align__(16) u16 Vs[256 * 64];   // 32 KB
  __shared__ __align__(16) u16 Cs[64 * 64];    // 8 KB
  const int tid = threadIdx.x;
  const int bh = blockIdx.x & 63;
  const int tt0 = (blockIdx.x >> 6) * 256;
  const int b = bh >> 4, h = bh & 15;
  const int lane = tid & 63, wave = tid >> 6;
  const int laneN = lane & 15, laneQ = lane >> 4;

  {
    const int r = tid >> 3, c = tid & 7;
#pragma unroll
    for (int i = 0; i < 8; ++i) {
      const int rr = r + i * 32;
      const u16* g = vb + (size_t)((tt0 + rr) * 4 + b) * 1024 + h * 64 + c * 8;
      g2l16(g, &Vs[rr * 64 + c * 8]);
    }
    const u16* gc = corrT + (size_t)bh * 4096 + tid * 8;
    g2l16(gc, &Cs[tid * 8]);
    g2l16(gc + 2048, &Cs[tid * 8 + 2048]);
  }
  __syncthreads();

  const int wt = wave * 64;
  f32x4 acc[4][4] = {};
#pragma unroll
  for (int ks = 0; ks < 64; ks += 32) {
    bf16x8 af[4], bf[4];
#pragma unroll
    for (int i = 0; i < 4; ++i)
      af[i] = *(const bf16x8*)&Vs[(wt + i * 16 + laneN) * 64 + ks + laneQ * 8];
#pragma unroll
    for (int j = 0; j < 4; ++j)
      bf[j] = *(const bf16x8*)&Cs[(j * 16 + laneN) * 64 + ks + laneQ * 8];
#pragma unroll
    for (int i = 0; i < 4; ++i)
#pragma unroll
      for (int j = 0; j < 4; ++j)
        acc[i][j] = __builtin_amdgcn_mfma_f32_16x16x32_bf16(af[i], bf[j], acc[i][j], 0, 0, 0);
  }
#pragma unroll
  for (int i = 0; i < 4; ++i)
#pragma unroll
    for (int j = 0; j < 4; ++j)
#pragma unroll
      for (int r = 0; r < 4; ++r) {
        const int t = tt0 + wt + i * 16 + laneQ * 4 + r;
        const int e = j * 16 + laneN;
        attnb[(size_t)(t * 4 + b) * 1024 + h * 64 + e] = f2b(acc[i][j][r]);
      }
}

// ---------------------------------------------------------------------------
// ws layout (bytes):
//   0          q_b    [32768,1024] bf16 (64 MiB; reused as attn out after stats)
//   67108864   k_b    [32768,1024] bf16
//   134217728  v_b    [32768,1024] bf16
//   201326592  Sqk    64*4096 f32 (1 MiB)
//   202375168  Smarg  4*4096 f32 (64 KiB)
//   202440704  corrT  64*4096 bf16 (512 KiB)
//   202964992  queryb [32768,1024] bf16 (64 MiB)
//   270073856  Wqkvb  [3072,1024] bf16 (6 MiB)
//   276365312  Woutb  [1024,1024] bf16 (2 MiB)     total ~265.6 MiB
// ---------------------------------------------------------------------------
extern "C" void kernel_launch(void* const* d_in, const int* in_sizes, int n_in,
                              void* d_out, int out_size, void* d_ws, size_t ws_size,
                              hipStream_t stream)
{
  const float* query = (const float*)d_in[0];
  const float* Wqkv  = (const float*)d_in[1];
  const float* bqkv  = (const float*)d_in[2];
  const float* Wout  = (const float*)d_in[3];
  const float* bout  = (const float*)d_in[4];
  float* out = (float*)d_out;
  char* ws = (char*)d_ws;

  u16*   qb     = (u16*)(ws);
  u16*   kb     = (u16*)(ws + 67108864);
  u16*   vb     = (u16*)(ws + 134217728);
  float* Sqk    = (float*)(ws + 201326592);
  float* Smarg  = (float*)(ws + 202375168);
  u16*   corrT  = (u16*)(ws + 202440704);
  u16*   queryb = (u16*)(ws + 202964992);
  u16*   Wqkvb  = (u16*)(ws + 270073856);
  u16*   Woutb  = (u16*)(ws + 276365312);

  // zero the atomic accumulators (ws is poisoned 0xAA before every launch)
  hipMemsetAsync(Sqk, 0, 1048576 + 65536, stream);

  // 0) fp32 -> bf16 copies of GEMM operands
  cvt_k<<<dim3(8192), dim3(256), 0, stream>>>(query, queryb, 33554432 / 8);
  cvt_k<<<dim3(1536), dim3(256), 0, stream>>>(Wqkv, Wqkvb, 3145728 / 8);
  cvt_k<<<dim3(512),  dim3(256), 0, stream>>>(Wout, Woutb, 1048576 / 8);

  // 1) qkv projection, split epilogue into q/k/v segments (bf16)
  gemm_bt<1><<<dim3(256 * 24), dim3(256), 0, stream>>>(queryb, Wqkvb, bqkv, qb,
                                                       32768, 3072, 1024, 24);
  // 2) covariance sums
  stats_k<<<dim3(1024), dim3(256), 0, stream>>>(qb, kb, Sqk, Smarg);
  // 3) corr + softmax -> corrT bf16
  finalize_k<<<dim3(64), dim3(64), 0, stream>>>(Sqk, Smarg, corrT);
  // 4) attn = v @ corr (writes into q_b, dead after stats)
  attn_k<<<dim3(64 * 32), dim3(256), 0, stream>>>(vb, corrT, qb);
  // 5) output projection, fp32 out
  gemm_bt<2><<<dim3(256 * 8), dim3(256), 0, stream>>>(qb, Woutb, bout, out,
                                                      32768, 1024, 1024, 8);
}